// Round 10
// baseline (235.060 us; speedup 1.0000x reference)
//
#include <hip/hip_runtime.h>
#include <cmath>

// LocalHolder2D: out = w3*log10(maxpool3(x)) + w5*log10(maxpool5(x)) + w7*log10(maxpool7(x))
// x: (8,64,256,256) fp32, strictly positive => -inf padding == 0 padding.
// One wave = 256-wide rows (64 lanes x float4), rolling down a 32-row strip.
//
// R1-R15: EVERY structural lever neutral at ~81us: MLP depth (R9), NT/cached
//   stores (R10), occupancy (R12), LDS staging (R13), continuous streaming
//   (R14), address-phase swizzle (R15). Time pinned while instr traffic
//   varied 291-582 MB. Deep-MLP variants all sit at 2.8-2.9 TB/s
//   INSTRUCTION-READ rate. Corpus read-side rates on this part: copy 3.15,
//   LN ~2.6, RMSNorm ~2.45 TB/s; pure-write fill 6.6. => demand-READ lane
//   ceiling ~3 TB/s chip-wide; we are at ~90% of it. All neutrals explained:
//   read-lane was saturated; byte-cutting variants (R13/R14) added their own
//   serialization and re-pinned.
// R16 (this): cut READ VOLUME, keep the proven deep-batch pipeline. 32-row
//   strip/wave: read amp 1.75 -> 38/32 = 1.19 (229 -> 159 MB). 14-reg
//   rolling window + ping-pong 4-row prefetch (pa/pb); per chunk: issue 4,
//   compute/store 4, counted vmcnt from the exact [L,S] FIFO; a batch is
//   only shifted into the window AFTER the wait that lands it. 38 loads +
//   32 stores per wave. Grid 512x8 = 4096 1-wave blocks = exactly one
//   16-wave/CU resident generation. Read floor 159MB/3.0 = 53us.

#define IMG_H 256
#define IMG_W 256
#define RPW   32    // output rows per wave (strip)

typedef float vf4 __attribute__((ext_vector_type(4)));

// volatile asm load: compiler cannot sink/reorder it; issues exactly where
// placed. saddr form: mem[s[base] + voff].
__device__ __forceinline__ vf4 aload(const float* base, uint32_t voff) {
  vf4 r;
  asm volatile("global_load_dwordx4 %0, %1, %2"
               : "=v"(r) : "v"(voff), "s"(base) : "memory");
  return r;
}

// Prologue: 18 loads issued (w0..w13, pa0..3); vmcnt(8) -> 10 oldest landed
// (w0..w9). Ties force consumers after the wait.
__device__ __forceinline__ void wait_pro(vf4& a, vf4& b, vf4& c, vf4& d,
                                         vf4& e, vf4& f, vf4& g, vf4& h,
                                         vf4& i, vf4& j) {
  asm volatile("s_waitcnt vmcnt(8)"
               : "+v"(a), "+v"(b), "+v"(c), "+v"(d), "+v"(e),
                 "+v"(f), "+v"(g), "+v"(h), "+v"(i), "+v"(j) :: "memory");
}

// c0: FIFO [w10-13, pa, pb, S0] (16) -> vmcnt(8) lands w10-13 + pa (8 regs).
__device__ __forceinline__ void wait_c0(vf4& a, vf4& b, vf4& c, vf4& d,
                                        vf4& e, vf4& f, vf4& g, vf4& h) {
  asm volatile("s_waitcnt vmcnt(8)"
               : "+v"(a), "+v"(b), "+v"(c), "+v"(d),
                 "+v"(e), "+v"(f), "+v"(g), "+v"(h) :: "memory");
}

// steady (c1..c4): FIFO [...prev stores..., BATCH, newer...] -> vmcnt(12)
// lands the batch issued LAST iter (4 regs).
__device__ __forceinline__ void wait_st(vf4& a, vf4& b, vf4& c, vf4& d) {
  asm volatile("s_waitcnt vmcnt(12)"
               : "+v"(a), "+v"(b), "+v"(c), "+v"(d) :: "memory");
}

// c5 (no new issue): FIFO [S3, pb, S4, S5] (16) -> vmcnt(8) lands pb.
__device__ __forceinline__ void wait_c5(vf4& a, vf4& b, vf4& c, vf4& d) {
  asm volatile("s_waitcnt vmcnt(8)"
               : "+v"(a), "+v"(b), "+v"(c), "+v"(d) :: "memory");
}

// lane i <- lane i-1, zero at lane 0  (DPP wf_shr1; invalid lane -> old=0)
__device__ __forceinline__ float dpp_left(float v) {
  return __int_as_float(
      __builtin_amdgcn_update_dpp(0, __float_as_int(v), 0x138, 0xF, 0xF, true));
}
// lane i <- lane i+1, zero at lane 63 (DPP wf_shl1)
__device__ __forceinline__ float dpp_right(float v) {
  return __int_as_float(
      __builtin_amdgcn_update_dpp(0, __float_as_int(v), 0x130, 0xF, 0xF, true));
}

__device__ __forceinline__ vf4 vmax(vf4 a, vf4 b) {
  vf4 r;
  r.x = fmaxf(a.x, b.x); r.y = fmaxf(a.y, b.y);
  r.z = fmaxf(a.z, b.z); r.w = fmaxf(a.w, b.w);
  return r;
}

struct PS { float p1, p2, p3, s1, s2, s3, f; };

__device__ __forceinline__ PS make_ps(vf4 a) {
  PS r;
  r.p1 = a.x;
  r.p2 = fmaxf(a.x, a.y);
  r.p3 = fmaxf(r.p2, a.z);
  r.s1 = a.w;
  r.s2 = fmaxf(a.z, a.w);
  r.s3 = fmaxf(a.y, r.s2);
  r.f  = fmaxf(r.p2, r.s2);
  return r;
}

// One output row from its 7-row input window (vertical max -> in-lane
// prefix/suffix + DPP neighbor exchange for horizontal max -> 3x log2).
__device__ __forceinline__ vf4 row_out(vf4 wm3, vf4 wm2, vf4 wm1, vf4 wc,
                                       vf4 wp1, vf4 wp2, vf4 wp3,
                                       float w3, float w5, float w7) {
  vf4 v1 = vmax(vmax(wm1, wc), wp1);
  vf4 v2 = vmax(v1, vmax(wm2, wp2));
  vf4 v3 = vmax(v2, vmax(wm3, wp3));

  PS a1 = make_ps(v1), a2 = make_ps(v2), a3 = make_ps(v3);

  float L1s1 = dpp_left(a1.s1);
  float L2s1 = dpp_left(a2.s1);
  float L2s2 = dpp_left(a2.s2);
  float L3s1 = dpp_left(a3.s1);
  float L3s2 = dpp_left(a3.s2);
  float L3s3 = dpp_left(a3.s3);

  float R1p1 = dpp_right(a1.p1);
  float R2p1 = dpp_right(a2.p1);
  float R2p2 = dpp_right(a2.p2);
  float R3p1 = dpp_right(a3.p1);
  float R3p2 = dpp_right(a3.p2);
  float R3p3 = dpp_right(a3.p3);

  float m3_0 = fmaxf(L1s1, a1.p2);
  float m3_1 = a1.p3;
  float m3_2 = a1.s3;
  float m3_3 = fmaxf(a1.s2, R1p1);

  float m5_0 = fmaxf(L2s2, a2.p3);
  float m5_1 = fmaxf(L2s1, a2.f);
  float m5_2 = fmaxf(a2.f, R2p1);
  float m5_3 = fmaxf(a2.s3, R2p2);

  float m7_0 = fmaxf(L3s3, a3.f);
  float m7_1 = fmaxf(fmaxf(L3s2, a3.f), R3p1);
  float m7_2 = fmaxf(fmaxf(L3s1, a3.f), R3p2);
  float m7_3 = fmaxf(a3.f, R3p3);

  vf4 o;
  o.x = fmaf(w7, __log2f(m7_0), fmaf(w5, __log2f(m5_0), w3 * __log2f(m3_0)));
  o.y = fmaf(w7, __log2f(m7_1), fmaf(w5, __log2f(m5_1), w3 * __log2f(m3_1)));
  o.z = fmaf(w7, __log2f(m7_2), fmaf(w5, __log2f(m5_2), w3 * __log2f(m3_2)));
  o.w = fmaf(w7, __log2f(m7_3), fmaf(w5, __log2f(m5_3), w3 * __log2f(m3_3)));
  return o;
}

__global__ __launch_bounds__(64, 4) void holder_kernel(
    const float* __restrict__ x, float* __restrict__ out,
    float w3, float w5, float w7)
{
  const int lane  = threadIdx.x;      // 64-thread block = one wave
  const int img   = blockIdx.x;       // 0..511
  const int strip = blockIdx.y;       // 0..7
  const int r0    = strip * RPW;

  const float* px = x + (size_t)img * (IMG_H * IMG_W);       // base (SGPR)
  float*       po = out + (size_t)img * (IMG_H * IMG_W) + lane * 4;
  const uint32_t lo = (uint32_t)lane * 16u;                  // byte off in row

  const vf4 vzero = (vf4)0.0f;

  // Rolling window: at chunk c, w[i] = input row r0 + 4c - 3 + i.
  vf4 w[14], pa[4], pb[4];

  // ---- prologue: rows r0-3..r0+10 -> w[0..13]; rows r0+11..14 -> pa.
  //      (max prologue row = 224+14 = 238: no high clamp needed)
#pragma unroll
  for (int i = 0; i < 14; ++i) {
    int rr = r0 - 3 + i;
    int rc = rr < 0 ? 0 : rr;
    w[i] = aload(px, (uint32_t)(rc * IMG_W * 4) + lo);
  }
#pragma unroll
  for (int j = 0; j < 4; ++j)
    pa[j] = aload(px, (uint32_t)((r0 + 11 + j) * IMG_W * 4) + lo);

  wait_pro(w[0], w[1], w[2], w[3], w[4], w[5], w[6], w[7], w[8], w[9]);
  if (r0 == 0) { w[0] = vzero; w[1] = vzero; w[2] = vzero; }  // rows -3..-1

  // ---- 8 chunks of 4 rows. Issue rows r0+15+4c at c=0..4 (rows through
  //      r0+34, the last row chunk 7's window needs). Counted waits derived
  //      from the exact FIFO (see helper comments); landed batch is shifted
  //      into w AFTER its wait. Bottom strip: only the c5-landed batch
  //      (rows r0+31..34) can exceed row 255 -> zero-fix there.
#pragma unroll
  for (int c = 0; c < 8; ++c) {
    // 1) issue this chunk's prefetch batch (ping-pong pa/pb)
    if (c < 5) {
      const int base = r0 + 15 + 4 * c;
#pragma unroll
      for (int j = 0; j < 4; ++j) {
        int rr = base + j;
        int rc = rr > IMG_H - 1 ? IMG_H - 1 : rr;
        if (c & 1) pa[j] = aload(px, (uint32_t)(rc * IMG_W * 4) + lo);
        else       pb[j] = aload(px, (uint32_t)(rc * IMG_W * 4) + lo);
      }
    }

    // 2) compute + store output rows r0+4c .. +3 from w[0..9]
#pragma unroll
    for (int j = 0; j < 4; ++j) {
      vf4 o = row_out(w[j], w[j + 1], w[j + 2], w[j + 3],
                      w[j + 4], w[j + 5], w[j + 6], w3, w5, w7);
      *(vf4*)(po + (r0 + 4 * c + j) * IMG_W) = o;
    }

    // 3) counted wait landing the batch that enters the window next,
    //    then shift window by 4 and swap ping-pong roles.
    if (c == 0) {
      wait_c0(w[10], w[11], w[12], w[13], pa[0], pa[1], pa[2], pa[3]);
#pragma unroll
      for (int i = 0; i < 10; ++i) w[i] = w[i + 4];
#pragma unroll
      for (int j = 0; j < 4; ++j) w[10 + j] = pa[j];
    } else if (c >= 1 && c <= 4) {
      // lands the batch issued at c-1: pb if (c-1) even, pa if odd
      if (c & 1) {  // c-1 even -> pb
        wait_st(pb[0], pb[1], pb[2], pb[3]);
#pragma unroll
        for (int i = 0; i < 10; ++i) w[i] = w[i + 4];
#pragma unroll
        for (int j = 0; j < 4; ++j) w[10 + j] = pb[j];
      } else {      // c-1 odd -> pa
        wait_st(pa[0], pa[1], pa[2], pa[3]);
#pragma unroll
        for (int i = 0; i < 10; ++i) w[i] = w[i + 4];
#pragma unroll
        for (int j = 0; j < 4; ++j) w[10 + j] = pa[j];
      }
    } else if (c == 5) {
      // lands pb (rows r0+31..34, issued at c=4); bottom zero-fix here
      wait_c5(pb[0], pb[1], pb[2], pb[3]);
#pragma unroll
      for (int j = 0; j < 4; ++j)
        if (r0 + 31 + j > IMG_H - 1) pb[j] = vzero;
#pragma unroll
      for (int i = 0; i < 10; ++i) w[i] = w[i + 4];
#pragma unroll
      for (int j = 0; j < 4; ++j) w[10 + j] = pb[j];
    } else if (c == 6) {
      // all rows already resident; pure shift (w[10..13] unused afterward)
#pragma unroll
      for (int i = 0; i < 10; ++i) w[i] = w[i + 4];
    }
    // c == 7: done; stores drain at endpgm
  }
}

extern "C" void kernel_launch(void* const* d_in, const int* in_sizes, int n_in,
                              void* d_out, int out_size, void* d_ws, size_t ws_size,
                              hipStream_t stream) {
  const float* x = (const float*)d_in[0];
  float* out = (float*)d_out;

  const int n_img = in_sizes[0] / (IMG_H * IMG_W);  // B*C = 512

  // closed-form OLS slope weights (H*W cancels in centering), log10(2) folded in
  const double l0 = log10(3.0), l1 = log10(5.0), l2 = log10(7.0);
  const double m  = (l0 + l1 + l2) / 3.0;
  const double c0 = l0 - m, c1 = l1 - m, c2 = l2 - m;
  const double s  = c0 * c0 + c1 * c1 + c2 * c2;
  const double LG2 = 0.30102999566398119521;  // log10(2)
  const float w3 = (float)(c0 / s * LG2);
  const float w5 = (float)(c1 / s * LG2);
  const float w7 = (float)(c2 / s * LG2);

  hipLaunchKernelGGL(holder_kernel, dim3(n_img, IMG_H / RPW), dim3(64),
                     0, stream, x, out, w3, w5, w7);
}